// Round 3
// baseline (66.729 us; speedup 1.0000x reference)
//
#include <hip/hip_runtime.h>

// Problem constants (from reference)
constexpr int NI      = 64;   // instances
constexpr int MM      = 28;   // mask resolution
constexpr int THING_C = 80;
constexpr int STUFF_C = 53;
constexpr int HH      = 512;
constexpr int WW      = 800;
constexpr int ROWS    = 16;   // rows per block (512 % 16 == 0)
constexpr int F_PER_ROW = WW / 4;         // 200 float4 per row
constexpr int F_PER_BLK = ROWS * F_PER_ROW; // 3200 float4 per block

// One block per (channel c, 16-row band). c in [0,117).
//  c < 53 : stuff channel -> verbatim band copy from sem_seg[c]
//  c >= 53: thing instance n = c-53 -> bilinear mask paste + cropped sem add
__global__ __launch_bounds__(256) void pan_kernel(
    const float* __restrict__ mask_logits,   // [64][80][28][28]
    const float* __restrict__ sem_seg,       // [133][512][800]
    const float* __restrict__ bboxes,        // [64][4]
    const int*   __restrict__ cls_idx,       // [64]
    float*       __restrict__ out)           // [117][512][800]
{
    const int yb = blockIdx.x * ROWS;   // band start row
    const int c  = blockIdx.y;          // 0..116
    const int t  = threadIdx.x;

    if (c < STUFF_C) {
        // ---- stuff: contiguous band copy (block-uniform branch) ----
        const float4* src = reinterpret_cast<const float4*>(
            sem_seg + ((size_t)c * HH + yb) * WW);
        float4* dst = reinterpret_cast<float4*>(
            out + ((size_t)c * HH + yb) * WW);
#pragma unroll 4
        for (int f = t; f < F_PER_BLK; f += 256) dst[f] = src[f];
        return;
    }

    // ---- thing channel ----
    const int n   = c - STUFF_C;
    const int cls = cls_idx[n];
    const float bx2f = bboxes[n * 4 + 2];
    const float by2f = bboxes[n * 4 + 3];
    const int x0 = (int)floorf(bboxes[n * 4 + 0]);
    const int y0 = (int)floorf(bboxes[n * 4 + 1]);
    const int x2 = (int)floorf(bx2f);
    const int y2 = (int)floorf(by2f);
    const float bwf = (float)(x2 - x0 + 1);
    const float bhf = (float)(y2 - y0 + 1);

    const int yin_lo = max(y0, 0);
    const int yin_hi = min(y2 + 1, HH);
    const int xin_lo = max(x0, 0);
    const int xin_hi = min(x2 + 1, WW);

    // crop box (jnp.round == rint, half-to-even)
    const int cy2 = (int)rintf(by2f) + 1;
    const int cx1 = x0;
    const int cx2 = (int)rintf(bx2f) + 1;

    // y-interpolated mask rows for the whole band
    __shared__ float fy[ROWS][MM];
    {
        const float* msk = mask_logits + (((size_t)n * THING_C + cls) * (MM * MM));
        for (int i = t; i < ROWS * MM; i += 256) {
            const int r   = i / MM;
            const int col = i - r * MM;
            const int y   = yb + r;
            float v = 0.0f;
            if (y >= yin_lo && y < yin_hi) {
                // src_y = clip((y - y0 + 0.5) * M / bh - 0.5, 0, M-1)  (ref op order)
                float sy = ((float)y - (float)y0 + 0.5f) * (float)MM / bhf - 0.5f;
                sy = fminf(fmaxf(sy, 0.0f), (float)(MM - 1));
                const int   iy0 = (int)floorf(sy);
                const int   iy1 = min(iy0 + 1, MM - 1);
                const float ly  = sy - (float)iy0;
                v = msk[iy0 * MM + col] * (1.0f - ly) + msk[iy1 * MM + col] * ly;
            }
            fy[r][col] = v;
        }
    }
    __syncthreads();

    const float* sem_base = sem_seg + (((size_t)(STUFF_C + cls) * HH + yb) * WW);
    float*       out_base = out     + (((size_t)c               * HH + yb) * WW);

    for (int f = t; f < F_PER_BLK; f += 256) {
        const int r     = f / F_PER_ROW;
        const int xbase = (f - r * F_PER_ROW) * 4;
        const int y     = yb + r;
        const bool row_in  = (y >= yin_lo) && (y < yin_hi);
        const bool crow_in = (y >= y0) && (y < cy2);

        float4 v;
        float* vp = reinterpret_cast<float*>(&v);
#pragma unroll
        for (int j = 0; j < 4; ++j) {
            const int x = xbase + j;
            float val = 0.0f;
            if (row_in && x >= xin_lo && x < xin_hi) {
                float sx = ((float)x - (float)x0 + 0.5f) * (float)MM / bwf - 0.5f;
                sx = fminf(fmaxf(sx, 0.0f), (float)(MM - 1));
                const int   ix0 = (int)floorf(sx);
                const int   ix1 = min(ix0 + 1, MM - 1);
                const float lx  = sx - (float)ix0;
                val = fy[r][ix0] * (1.0f - lx) + fy[r][ix1] * lx;
            }
            if (crow_in && x >= cx1 && x < cx2) {
                val += sem_base[(size_t)r * WW + x];
            }
            vp[j] = val;
        }
        *reinterpret_cast<float4*>(out_base + (size_t)r * WW + xbase) = v;
    }
}

extern "C" void kernel_launch(void* const* d_in, const int* in_sizes, int n_in,
                              void* d_out, int out_size, void* d_ws, size_t ws_size,
                              hipStream_t stream) {
    const float* mask_logits = (const float*)d_in[0];  // 64*80*28*28
    const float* sem_seg     = (const float*)d_in[1];  // 133*512*800
    const float* bboxes      = (const float*)d_in[2];  // 64*4
    const int*   cls_idx     = (const int*)d_in[3];    // 64
    float*       out         = (float*)d_out;          // 117*512*800

    dim3 grid(HH / ROWS, STUFF_C + NI);   // (32, 117) = 3744 blocks
    pan_kernel<<<grid, 256, 0, stream>>>(mask_logits, sem_seg, bboxes, cls_idx, out);
}

// Round 5
// 60.431 us; speedup vs baseline: 1.1042x; 1.1042x over previous
//
#include <hip/hip_runtime.h>

// Problem constants (from reference)
constexpr int NI      = 64;   // instances
constexpr int MM      = 28;   // mask resolution
constexpr int THING_C = 80;
constexpr int STUFF_C = 53;
constexpr int HH      = 512;
constexpr int WW      = 800;
constexpr int ROWS    = 16;   // rows per block (512 % 16 == 0)
constexpr int F_PER_ROW = WW / 4;           // 200 float4 per row
constexpr int F_PER_BLK = ROWS * F_PER_ROW; // 3200 float4 per block

// clang native vector type — __builtin_nontemporal_* requires a real vector,
// not HIP's struct-based float4.
typedef float vfloat4 __attribute__((ext_vector_type(4)));

// One block per (channel c, 16-row band). c in [0,117).
//  c < 53 : stuff channel -> verbatim band copy from sem_seg[c] (NT both ways)
//  c >= 53: thing instance n = c-53 -> bilinear mask paste + cropped sem add
// All output stores are nontemporal: out is write-once/read-never, keep it
// out of L2/LLC so the read streams keep their cache.
__global__ __launch_bounds__(256) void pan_kernel(
    const float* __restrict__ mask_logits,   // [64][80][28][28]
    const float* __restrict__ sem_seg,       // [133][512][800]
    const float* __restrict__ bboxes,        // [64][4]
    const int*   __restrict__ cls_idx,       // [64]
    float*       __restrict__ out)           // [117][512][800]
{
    const int yb = blockIdx.x * ROWS;   // band start row
    const int c  = blockIdx.y;          // 0..116
    const int t  = threadIdx.x;

    if (c < STUFF_C) {
        // ---- stuff: contiguous band copy, nontemporal (read-once/write-once)
        const vfloat4* src = reinterpret_cast<const vfloat4*>(
            sem_seg + ((size_t)c * HH + yb) * WW);
        vfloat4* dst = reinterpret_cast<vfloat4*>(
            out + ((size_t)c * HH + yb) * WW);
#pragma unroll 4
        for (int f = t; f < F_PER_BLK; f += 256) {
            vfloat4 v = __builtin_nontemporal_load(src + f);
            __builtin_nontemporal_store(v, dst + f);
        }
        return;
    }

    // ---- thing channel ----
    const int n   = c - STUFF_C;
    const int cls = cls_idx[n];
    const float bx2f = bboxes[n * 4 + 2];
    const float by2f = bboxes[n * 4 + 3];
    const int x0 = (int)floorf(bboxes[n * 4 + 0]);
    const int y0 = (int)floorf(bboxes[n * 4 + 1]);
    const int x2 = (int)floorf(bx2f);
    const int y2 = (int)floorf(by2f);
    const float bwf = (float)(x2 - x0 + 1);
    const float bhf = (float)(y2 - y0 + 1);

    const int yin_lo = max(y0, 0);
    const int yin_hi = min(y2 + 1, HH);
    const int xin_lo = max(x0, 0);
    const int xin_hi = min(x2 + 1, WW);

    // crop box (jnp.round == rint, half-to-even)
    const int cy2 = (int)rintf(by2f) + 1;
    const int cx1 = x0;
    const int cx2 = (int)rintf(bx2f) + 1;

    // y-interpolated mask rows for the whole band
    __shared__ float fy[ROWS][MM];
    {
        const float* msk = mask_logits + (((size_t)n * THING_C + cls) * (MM * MM));
        for (int i = t; i < ROWS * MM; i += 256) {
            const int r   = i / MM;
            const int col = i - r * MM;
            const int y   = yb + r;
            float v = 0.0f;
            if (y >= yin_lo && y < yin_hi) {
                // src_y = clip((y - y0 + 0.5) * M / bh - 0.5, 0, M-1)  (ref op order)
                float sy = ((float)y - (float)y0 + 0.5f) * (float)MM / bhf - 0.5f;
                sy = fminf(fmaxf(sy, 0.0f), (float)(MM - 1));
                const int   iy0 = (int)floorf(sy);
                const int   iy1 = min(iy0 + 1, MM - 1);
                const float ly  = sy - (float)iy0;
                v = msk[iy0 * MM + col] * (1.0f - ly) + msk[iy1 * MM + col] * ly;
            }
            fy[r][col] = v;
        }
    }
    __syncthreads();

    const float* sem_base = sem_seg + (((size_t)(STUFF_C + cls) * HH + yb) * WW);
    float*       out_base = out     + (((size_t)c               * HH + yb) * WW);

    for (int f = t; f < F_PER_BLK; f += 256) {
        const int r     = f / F_PER_ROW;
        const int xbase = (f - r * F_PER_ROW) * 4;
        const int y     = yb + r;
        const bool row_in  = (y >= yin_lo) && (y < yin_hi);
        const bool crow_in = (y >= y0) && (y < cy2);

        vfloat4 v;
#pragma unroll
        for (int j = 0; j < 4; ++j) {
            const int x = xbase + j;
            float val = 0.0f;
            if (row_in && x >= xin_lo && x < xin_hi) {
                float sx = ((float)x - (float)x0 + 0.5f) * (float)MM / bwf - 0.5f;
                sx = fminf(fmaxf(sx, 0.0f), (float)(MM - 1));
                const int   ix0 = (int)floorf(sx);
                const int   ix1 = min(ix0 + 1, MM - 1);
                const float lx  = sx - (float)ix0;
                val = fy[r][ix0] * (1.0f - lx) + fy[r][ix1] * lx;
            }
            v[j] = val;
        }

        if (crow_in) {
            if (xbase >= cx1 && xbase + 3 < cx2) {
                // whole float4 inside crop box: one aligned vector load
                const vfloat4 s = *reinterpret_cast<const vfloat4*>(
                    sem_base + (size_t)r * WW + xbase);
                v += s;
            } else {
#pragma unroll
                for (int j = 0; j < 4; ++j) {
                    const int x = xbase + j;
                    if (x >= cx1 && x < cx2)
                        v[j] += sem_base[(size_t)r * WW + x];
                }
            }
        }
        __builtin_nontemporal_store(v,
            reinterpret_cast<vfloat4*>(out_base + (size_t)r * WW + xbase));
    }
}

extern "C" void kernel_launch(void* const* d_in, const int* in_sizes, int n_in,
                              void* d_out, int out_size, void* d_ws, size_t ws_size,
                              hipStream_t stream) {
    const float* mask_logits = (const float*)d_in[0];  // 64*80*28*28
    const float* sem_seg     = (const float*)d_in[1];  // 133*512*800
    const float* bboxes      = (const float*)d_in[2];  // 64*4
    const int*   cls_idx     = (const int*)d_in[3];    // 64
    float*       out         = (float*)d_out;          // 117*512*800

    dim3 grid(HH / ROWS, STUFF_C + NI);   // (32, 117) = 3744 blocks
    pan_kernel<<<grid, 256, 0, stream>>>(mask_logits, sem_seg, bboxes, cls_idx, out);
}

// Round 6
// 48.241 us; speedup vs baseline: 1.3832x; 1.2527x over previous
//
#include <hip/hip_runtime.h>

// Problem constants (from reference)
constexpr int NI      = 64;   // instances
constexpr int MM      = 28;   // mask resolution
constexpr int THING_C = 80;
constexpr int STUFF_C = 53;
constexpr int HH      = 512;
constexpr int WW      = 800;
constexpr int F_PER_ROW = WW / 4;   // 200 float4 per row

// clang native vector type — __builtin_nontemporal_* requires a real vector,
// not HIP's struct-based float4.
typedef float vfloat4 __attribute__((ext_vector_type(4)));

// One block per output row (c, y), c in [0,117).
//  c < 53         : stuff channel -> NT row copy from sem_seg[c]
//  c >= 53, no box: NT zero fill (block-uniform fast path, no LDS/barrier)
//  c >= 53, in box: bilinear mask paste + cropped sem add
// Output is write-once/read-never: all stores nontemporal to keep the 192 MB
// write stream out of L2/LLC (R4: +10%).
__global__ __launch_bounds__(256) void pan_kernel(
    const float* __restrict__ mask_logits,   // [64][80][28][28]
    const float* __restrict__ sem_seg,       // [133][512][800]
    const float* __restrict__ bboxes,        // [64][4]
    const int*   __restrict__ cls_idx,       // [64]
    float*       __restrict__ out)           // [117][512][800]
{
    const int y = blockIdx.x;   // 0..511
    const int c = blockIdx.y;   // 0..116
    const int t = threadIdx.x;

    if (c < STUFF_C) {
        // ---- stuff: contiguous NT row copy ----
        if (t < F_PER_ROW) {
            const vfloat4* src = reinterpret_cast<const vfloat4*>(
                sem_seg + ((size_t)c * HH + y) * WW);
            vfloat4* dst = reinterpret_cast<vfloat4*>(
                out + ((size_t)c * HH + y) * WW);
            __builtin_nontemporal_store(__builtin_nontemporal_load(src + t),
                                        dst + t);
        }
        return;
    }

    // ---- thing channel ----
    const int n   = c - STUFF_C;
    const int cls = cls_idx[n];
    const float bx2f = bboxes[n * 4 + 2];
    const float by2f = bboxes[n * 4 + 3];
    const int x0 = (int)floorf(bboxes[n * 4 + 0]);
    const int y0 = (int)floorf(bboxes[n * 4 + 1]);
    const int x2 = (int)floorf(bx2f);
    const int y2 = (int)floorf(by2f);

    // mask-paste row validity and crop-row validity (jnp.round == rint)
    const bool row_in  = (y >= max(y0, 0)) && (y < min(y2 + 1, HH));
    const int  cy2     = (int)rintf(by2f) + 1;
    const bool crow_in = (y >= y0) && (y < cy2);

    vfloat4* out_row4 = reinterpret_cast<vfloat4*>(
        out + (((size_t)c * HH + y) * WW));

    if (!row_in && !crow_in) {
        // ---- fast path: row entirely outside both boxes -> NT zero fill ----
        if (t < F_PER_ROW) {
            vfloat4 z = {0.0f, 0.0f, 0.0f, 0.0f};
            __builtin_nontemporal_store(z, out_row4 + t);
        }
        return;
    }

    const float bwf = (float)(x2 - x0 + 1);
    const float bhf = (float)(y2 - y0 + 1);
    const int xin_lo = max(x0, 0);
    const int xin_hi = min(x2 + 1, WW);
    const int cx1 = x0;
    const int cx2 = (int)rintf(bx2f) + 1;

    // y-interpolated mask row (28 entries) in LDS
    __shared__ float fy_row[MM];
    if (row_in && t < MM) {
        // src_y = clip((y - y0 + 0.5) * M / bh - 0.5, 0, M-1)  (ref op order)
        float sy = ((float)y - (float)y0 + 0.5f) * (float)MM / bhf - 0.5f;
        sy = fminf(fmaxf(sy, 0.0f), (float)(MM - 1));
        const int   iy0 = (int)floorf(sy);
        const int   iy1 = min(iy0 + 1, MM - 1);
        const float ly  = sy - (float)iy0;
        const float* msk = mask_logits + (((size_t)n * THING_C + cls) * (MM * MM));
        fy_row[t] = msk[iy0 * MM + t] * (1.0f - ly) + msk[iy1 * MM + t] * ly;
    }
    __syncthreads();

    if (t >= F_PER_ROW) return;      // 200 active lanes
    const int xbase = t * 4;

    const float* sem_row = sem_seg + (((size_t)(STUFF_C + cls) * HH + y) * WW);

    vfloat4 v;
#pragma unroll
    for (int j = 0; j < 4; ++j) {
        const int x = xbase + j;
        float val = 0.0f;
        if (row_in && x >= xin_lo && x < xin_hi) {
            float sx = ((float)x - (float)x0 + 0.5f) * (float)MM / bwf - 0.5f;
            sx = fminf(fmaxf(sx, 0.0f), (float)(MM - 1));
            const int   ix0 = (int)floorf(sx);
            const int   ix1 = min(ix0 + 1, MM - 1);
            const float lx  = sx - (float)ix0;
            val = fy_row[ix0] * (1.0f - lx) + fy_row[ix1] * lx;
        }
        v[j] = val;
    }

    if (crow_in) {
        if (xbase >= cx1 && xbase + 3 < cx2) {
            // whole float4 inside crop box: one aligned vector load
            v += *reinterpret_cast<const vfloat4*>(sem_row + xbase);
        } else {
#pragma unroll
            for (int j = 0; j < 4; ++j) {
                const int x = xbase + j;
                if (x >= cx1 && x < cx2) v[j] += sem_row[x];
            }
        }
    }
    __builtin_nontemporal_store(v, out_row4 + t);
}

extern "C" void kernel_launch(void* const* d_in, const int* in_sizes, int n_in,
                              void* d_out, int out_size, void* d_ws, size_t ws_size,
                              hipStream_t stream) {
    const float* mask_logits = (const float*)d_in[0];  // 64*80*28*28
    const float* sem_seg     = (const float*)d_in[1];  // 133*512*800
    const float* bboxes      = (const float*)d_in[2];  // 64*4
    const int*   cls_idx     = (const int*)d_in[3];    // 64
    float*       out         = (float*)d_out;          // 117*512*800

    dim3 grid(HH, STUFF_C + NI);   // (512, 117) -> one block per output row
    pan_kernel<<<grid, 256, 0, stream>>>(mask_logits, sem_seg, bboxes, cls_idx, out);
}